// Round 10
// baseline (607.304 us; speedup 1.0000x reference)
//
#include <hip/hip_runtime.h>
#include <hip/hip_bf16.h>

#define NEG 0.01f
#define EPS 1e-5f

typedef __attribute__((ext_vector_type(8))) short short8;
typedef __attribute__((ext_vector_type(4))) float floatx4;

__device__ inline unsigned short f2bf(float f) {
    __hip_bfloat16 h = __float2bfloat16(f);
    union { __hip_bfloat16 h; unsigned short u; } cv; cv.h = h;
    return cv.u;
}

// -------------------- device-wide barrier (256 co-resident blocks) ----------
// __syncthreads drains the block's vmcnt (stores in L2); tid0's __threadfence
// emits the agent-scope L2 writeback (gfx950: buffer_wbl2) making them visible
// across XCDs; acquire side invalidates. Counters pre-zeroed by host memset.
__device__ __forceinline__ void gbar(unsigned* __restrict__ bar, int phase) {
    __syncthreads();
    if (threadIdx.x == 0) {
        __threadfence();
        __hip_atomic_fetch_add(&bar[phase], 1u, __ATOMIC_RELEASE, __HIP_MEMORY_SCOPE_AGENT);
        while (__hip_atomic_load(&bar[phase], __ATOMIC_ACQUIRE, __HIP_MEMORY_SCOPE_AGENT) < 256u)
            __builtin_amdgcn_s_sleep(8);
        __threadfence();
    }
    __syncthreads();
}

// ------------------------------- conv phase (proven R5/R8 structure) --------
// NW waves, direct-global A frags, LDS double-buffered B (one barrier per
// CH-step chunk), optional K-split, optional fused BN stats.
template <int CP, int COUT, int HP, int LOG_OHW, int LOG_OW, int SUB,
          int NCO, int NT, int CH, int NW, int KS, bool STATS>
__device__ __forceinline__ void conv_phase(int bid, int tid,
        const unsigned short* __restrict__ inP,
        const unsigned short* __restrict__ wT,
        float* __restrict__ out, float* __restrict__ stacc,
        char* __restrict__ smemRaw) {
    constexpr int NSTEP = 5 * SUB;
    constexpr int SSTEP = NSTEP / KS;
    constexpr int NCHUNK = SSTEP / CH;
    constexpr int COT = NT * 16;
    constexpr int NSTG = (CH * COT * 4) / (NW * 64);
    constexpr int NM = 256 / (KS * NCO);
    constexpr int M = NM * NW * 64;
    typedef short (*BsT)[CH][COT][32];
    BsT Bs = (BsT)smemRaw;
    float* sred = (float*)(smemRaw + 2 * CH * COT * 32 * 2);  // [NW][2][COT]
    int wave = tid >> 6, lane = tid & 63, q = lane >> 4, l16 = lane & 15;
    int ks = bid / (NM * NCO);
    int rem = bid - ks * (NM * NCO);
    int bm = rem / NCO, bco = rem % NCO;
    int sbase = ks * SSTEP;

    const short* aB[4];
#pragma unroll
    for (int f = 0; f < 4; ++f) {
        int m = bm * (NW * 64) + wave * 64 + f * 16 + l16;
        int b = m >> LOG_OHW;
        int ohw = m & ((1 << LOG_OHW) - 1);
        int oh = ohw >> LOG_OW, ow = ohw & ((1 << LOG_OW) - 1);
        aB[f] = (const short*)inP + ((size_t)((b * HP + 2 * oh) * HP + 2 * ow)) * CP + q * 8;
    }
    const short* bgbase = (const short*)wT + (size_t)bco * COT * 32;

    floatx4 acc[4][NT];
#pragma unroll
    for (int f = 0; f < 4; ++f)
#pragma unroll
        for (int nt = 0; nt < NT; ++nt) acc[f][nt] = (floatx4){0.f, 0.f, 0.f, 0.f};

    short8 nb[NSTG];
#pragma unroll
    for (int i = 0; i < NSTG; ++i) {
        int v = tid + i * NW * 64;
        int s = v / (COT * 4);
        int r2 = v - s * (COT * 4);
        nb[i] = *(const short8*)(bgbase + ((size_t)(sbase + s) * COUT) * 32 + r2 * 8);
    }
#pragma unroll
    for (int i = 0; i < NSTG; ++i) {
        int v = tid + i * NW * 64;
        int s = v / (COT * 4);
        int r2 = v - s * (COT * 4);
        *(short8*)((short*)&Bs[0][s][0][0] + r2 * 8) = nb[i];
    }
    __syncthreads();

    for (int chunk = 0; chunk < NCHUNK; ++chunk) {
        int cur = chunk & 1;
        if (chunk + 1 < NCHUNK) {
            int step0 = sbase + (chunk + 1) * CH;
#pragma unroll
            for (int i = 0; i < NSTG; ++i) {
                int v = tid + i * NW * 64;
                int s = v / (COT * 4);
                int r2 = v - s * (COT * 4);
                nb[i] = *(const short8*)(bgbase + ((size_t)(step0 + s) * COUT) * 32 + r2 * 8);
            }
        }
#pragma unroll
        for (int s = 0; s < CH; ++s) {
            int gstep = sbase + chunk * CH + s;
            int kh = gstep / SUB, sub = gstep - kh * SUB;
            short8 af[4];
#pragma unroll
            for (int f = 0; f < 4; ++f)
                af[f] = *(const short8*)(aB[f] + (size_t)(kh * HP) * CP + sub * 32);
#pragma unroll
            for (int nt = 0; nt < NT; ++nt) {
                short8 bf = *(const short8*)&Bs[cur][s][nt * 16 + l16][q * 8];
#pragma unroll
                for (int f = 0; f < 4; ++f)
                    acc[f][nt] = __builtin_amdgcn_mfma_f32_16x16x32_bf16(af[f], bf, acc[f][nt], 0, 0, 0);
            }
        }
        if (chunk + 1 < NCHUNK) {
#pragma unroll
            for (int i = 0; i < NSTG; ++i) {
                int v = tid + i * NW * 64;
                int s = v / (COT * 4);
                int r2 = v - s * (COT * 4);
                *(short8*)((short*)&Bs[cur ^ 1][s][0][0] + r2 * 8) = nb[i];
            }
            __syncthreads();
        }
    }
    float* outK = out + (size_t)ks * M * COUT;
#pragma unroll
    for (int f = 0; f < 4; ++f)
#pragma unroll
        for (int nt = 0; nt < NT; ++nt)
#pragma unroll
            for (int rg = 0; rg < 4; ++rg) {
                int mg = bm * (NW * 64) + wave * 64 + f * 16 + q * 4 + rg;
                int co = bco * COT + nt * 16 + l16;
                outK[(size_t)mg * COUT + co] = acc[f][nt][rg];
            }
    if (STATS) {
#pragma unroll
        for (int nt = 0; nt < NT; ++nt) {
            float s = 0.f, s2 = 0.f;
#pragma unroll
            for (int f = 0; f < 4; ++f)
#pragma unroll
                for (int rg = 0; rg < 4; ++rg) {
                    float v = acc[f][nt][rg];
                    s += v; s2 = fmaf(v, v, s2);
                }
            s += __shfl_xor(s, 16); s += __shfl_xor(s, 32);
            s2 += __shfl_xor(s2, 16); s2 += __shfl_xor(s2, 32);
            if (q == 0) {
                sred[(wave * 2 + 0) * COT + nt * 16 + l16] = s;
                sred[(wave * 2 + 1) * COT + nt * 16 + l16] = s2;
            }
        }
        __syncthreads();
        if (tid < COT) {
            float ts = 0.f, ts2 = 0.f;
#pragma unroll
            for (int w = 0; w < NW; ++w) {
                ts += sred[(w * 2 + 0) * COT + tid];
                ts2 += sred[(w * 2 + 1) * COT + tid];
            }
            atomicAdd(&stacc[bco * COT + tid], ts);
            atomicAdd(&stacc[COUT + bco * COT + tid], ts2);
        }
    }
}

// -------------------- BN finalize + lrelu + pad + bf16 (vectorized x8) ------
template <int CO_LOG, int OH, int OHP, int ITERS>
__device__ __forceinline__ void bnpad_phase(int bid, int tid,
        const float* __restrict__ X, const float* __restrict__ stacc,
        const float* __restrict__ g, const float* __restrict__ bb,
        unsigned short* __restrict__ out, float invN, char* __restrict__ smemRaw) {
    constexpr int CO = 1 << CO_LOG;
    constexpr int TOTALV = 64 * OHP * OHP * (CO / 8);
    float* sc_s = (float*)smemRaw;
    float* sh_s = sc_s + CO;
    if (tid < CO) {
        float mean = stacc[tid] * invN;
        float var = fmaxf(stacc[CO + tid] * invN - mean * mean, 0.f);
        float sc = g[tid] * rsqrtf(var + EPS);
        sc_s[tid] = sc;
        sh_s[tid] = bb[tid] - mean * sc;
    }
    __syncthreads();
    for (int i = 0; i < ITERS; ++i) {
        int u = i * 65536 + (bid << 8) + tid;
        if (u >= TOTALV) break;
        int c0 = (u & (CO / 8 - 1)) << 3;
        int t = u >> (CO_LOG - 3);
        int x = t % OHP; t /= OHP;
        int y = t % OHP; int b = t / OHP;
        short8 sv;
        if (y >= 2 && y < OH + 2 && x >= 2 && x < OH + 2) {
            const float* src = X + (((size_t)((b * OH + (y - 2)) * OH + (x - 2))) << CO_LOG) + c0;
            float4 a0 = *(const float4*)src;
            float4 a1 = *(const float4*)(src + 4);
            float vals[8] = {a0.x, a0.y, a0.z, a0.w, a1.x, a1.y, a1.z, a1.w};
#pragma unroll
            for (int j = 0; j < 8; ++j) {
                float f = vals[j] * sc_s[c0 + j] + sh_s[c0 + j];
                f = f >= 0.f ? f : NEG * f;
                sv[j] = (short)f2bf(f);
            }
        } else {
#pragma unroll
            for (int j = 0; j < 8; ++j) sv[j] = 0;
        }
        *(short8*)(out + (size_t)u * 8) = sv;
    }
}

// --------------------------------------------------------------- mega -------
__global__ __launch_bounds__(256) void mega_kernel(
        const float* __restrict__ input_data,
        const float* __restrict__ w1, const float* __restrict__ g1, const float* __restrict__ b1,
        const float* __restrict__ w2, const float* __restrict__ g2, const float* __restrict__ b2,
        const float* __restrict__ w3, const float* __restrict__ g3, const float* __restrict__ b3,
        const float* __restrict__ w4, const float* __restrict__ g4, const float* __restrict__ b4,
        const float* __restrict__ w5, const float* __restrict__ b5,
        unsigned short* __restrict__ rendered,
        float* __restrict__ conv1out, unsigned short* __restrict__ pad1,
        float* __restrict__ conv2out, unsigned short* __restrict__ pad2,
        float* __restrict__ conv3parts, unsigned short* __restrict__ a4,
        float* __restrict__ h4,
        float* __restrict__ st1, float* __restrict__ st2,
        float* __restrict__ st3, float* __restrict__ st4,
        unsigned short* __restrict__ wT1, unsigned short* __restrict__ wT2,
        unsigned short* __restrict__ wT3,
        unsigned* __restrict__ bar,
        float* __restrict__ outF) {
    __shared__ __align__(16) char smem[43008];
    int tid = threadIdx.x;
    int bid = blockIdx.x;

    // ---------------- phase 0: render (4 units/block) + weight transforms ---
    {
        float* r0 = (float*)smem;           // 46
        float* r1 = r0 + 46; float* r2 = r1 + 46; float* r3 = r2 + 46;
        float* cls_s = r3 + 46;             // 46*14
        for (int u = 0; u < 4; ++u) {
            __syncthreads();
            int rb = bid + u * 256;
            int b = rb >> 4, chunk = rb & 15;
            if (tid < 46) {
                const float* p = input_data + ((size_t)b * 46 + tid) * 18 + 14;
                float x = p[0] * 64.f, y = p[1] * 64.f, w = p[2] * 64.f, h = p[3] * 64.f;
                r0[tid] = x - 0.5f * w; r1[tid] = x + 0.5f * w;
                r2[tid] = y - 0.5f * h; r3[tid] = y + 0.5f * h;
            }
            for (int idx = tid; idx < 46 * 14; idx += 256) {
                int n = idx / 14, c = idx % 14;
                cls_s[idx] = input_data[((size_t)b * 46 + n) * 18 + c];
            }
            __syncthreads();
            if (tid < 33) {
                int j = chunk * 33 + tid;
                if (j < 528) {
                    int y, x;
                    if (j < 136) { y = j / 68; x = j - y * 68; }
                    else if (j < 272) { int t = j - 136; int yy = t / 68; y = 66 + yy; x = t - yy * 68; }
                    else { int t = j - 272; y = 2 + (t >> 2); int k = t & 3; x = (k < 2) ? k : 64 + k; }
                    size_t zb = (((size_t)b * 68 + y) * 68 + x) * 16;
                    short8 z;
#pragma unroll
                    for (int i = 0; i < 8; ++i) z[i] = 0;
                    *(short8*)(rendered + zb) = z;
                    *(short8*)(rendered + zb + 8) = z;
                }
            }
            int pix = chunk * 256 + tid;
            float cx = (float)(pix & 63);
            float cy = (float)(pix >> 6);
            float acc[14];
#pragma unroll
            for (int c = 0; c < 14; ++c) acc[c] = 0.f;
            for (int n = 0; n < 46; ++n) {
                float x0 = r0[n], x1 = r1[n], y0 = r2[n], y1 = r3[n];
                float by = fminf(fmaxf(cy - y0, 0.f), 1.f) * fminf(fmaxf(y1 - cy, 0.f), 1.f);
                float bx = fminf(fmaxf(cx - x0, 0.f), 1.f) * fminf(fmaxf(x1 - cx, 0.f), 1.f);
                float kx0 = fmaxf(1.f - fabsf(cx - x0), 0.f);
                float kx1 = fmaxf(1.f - fabsf(cx - x1), 0.f);
                float ky0 = fmaxf(1.f - fabsf(cy - y0), 0.f);
                float ky1 = fmaxf(1.f - fabsf(cy - y1), 0.f);
                float r = fmaxf(fmaxf(kx0 * by, kx1 * by), fmaxf(ky0 * bx, ky1 * bx));
                if (r > 0.f) {
#pragma unroll
                    for (int c = 0; c < 14; ++c) acc[c] = fmaf(cls_s[n * 14 + c], r, acc[c]);
                }
            }
            size_t ob = (((size_t)b * 68 + ((pix >> 6) + 2)) * 68 + ((pix & 63) + 2)) * 16;
            short8 v0, v1;
#pragma unroll
            for (int i = 0; i < 8; ++i) v0[i] = (short)f2bf(acc[i]);
#pragma unroll
            for (int i = 0; i < 6; ++i) v1[i] = (short)f2bf(acc[8 + i]);
            v1[6] = 0; v1[7] = 0;
            *(short8*)(rendered + ob) = v0;
            *(short8*)(rendered + ob + 8) = v1;
        }
        // weight transforms (grid-stride, no LDS)
        for (int i = 0; i < 17; ++i) {
            int idx = i * 65536 + (bid << 8) + tid;
            if (idx >= 1054720) break;
            const float* w; unsigned short* wT; int CIN, CPLOG, SUB, COLOG;
            if (idx < 30720) { w = w1; wT = wT1; CIN = 14; CPLOG = 4; SUB = 3; COLOG = 6; }
            else if (idx < 235520) { idx -= 30720; w = w2; wT = wT2; CIN = 64; CPLOG = 6; SUB = 10; COLOG = 7; }
            else { idx -= 235520; w = w3; wT = wT3; CIN = 128; CPLOG = 7; SUB = 20; COLOG = 8; }
            int kk = idx & 31;
            int co = (idx >> 5) & ((1 << COLOG) - 1);
            int s = idx >> (5 + COLOG);
            int kh = s / SUB, sub = s - kh * SUB;
            int kidx = sub * 32 + kk;
            int kw = kidx >> CPLOG;
            int ci = kidx & ((1 << CPLOG) - 1);
            float v = (kw < 5 && ci < CIN) ? w[((size_t)(co * CIN + ci) * 5 + kh) * 5 + kw] : 0.f;
            wT[idx] = f2bf(v);
        }
    }
    gbar(bar, 0);

    // ---------------- phase 1: conv1 + fused stats --------------------------
    conv_phase<16, 64, 68, 10, 5, 3, 1, 4, 5, 4, 1, true>(bid, tid, rendered, wT1, conv1out, st1, smem);
    gbar(bar, 1);

    // ---------------- phase 2: bnpad1 ---------------------------------------
    bnpad_phase<6, 32, 36, 11>(bid, tid, conv1out, st1, g1, b1, pad1, 1.f / 65536.f, smem);
    gbar(bar, 2);

    // ---------------- phase 3: conv2 + fused stats --------------------------
    conv_phase<64, 128, 36, 8, 4, 10, 4, 2, 10, 4, 1, true>(bid, tid, pad1, wT2, conv2out, st2, smem);
    gbar(bar, 3);

    // ---------------- phase 4: bnpad2 ---------------------------------------
    bnpad_phase<7, 16, 20, 7>(bid, tid, conv2out, st2, g2, b2, pad2, 1.f / 16384.f, smem);
    gbar(bar, 4);

    // ---------------- phase 5: conv3 (KS=2 partials) ------------------------
    conv_phase<128, 256, 20, 6, 3, 20, 8, 2, 10, 4, 2, false>(bid, tid, pad2, wT3, conv3parts, (float*)0, smem);
    gbar(bar, 5);

    // ---------------- phase 6: stats3 (partial-sum) -------------------------
    {
        float* ls = (float*)smem;
        float* ls2 = ls + 256;
        int cg = bid & 3, rb = bid >> 2;
        int c = (cg << 6) + (tid & 63);
        int w = tid >> 6;
        float s = 0.f, s2 = 0.f;
        for (int r = rb * 64 + w; r < rb * 64 + 64; r += 4) {
            float v = conv3parts[(size_t)r * 256 + c] + conv3parts[1048576 + (size_t)r * 256 + c];
            s += v; s2 += v * v;
        }
        ls[(w << 6) + (tid & 63)] = s;
        ls2[(w << 6) + (tid & 63)] = s2;
        __syncthreads();
        if (tid < 64) {
            float ts = ls[tid] + ls[64 + tid] + ls[128 + tid] + ls[192 + tid];
            float ts2 = ls2[tid] + ls2[64 + tid] + ls2[128 + tid] + ls2[192 + tid];
            atomicAdd(&st3[(cg << 6) + tid], ts);
            atomicAdd(&st3[256 + (cg << 6) + tid], ts2);
        }
    }
    gbar(bar, 6);

    // ---------------- phase 7: bn_nchw -> a4 --------------------------------
    {
        float* sc_s = (float*)smem;
        float* sh_s = sc_s + 256;
        {
            float mean = st3[tid] * (1.f / 4096.f);
            float var = fmaxf(st3[256 + tid] * (1.f / 4096.f) - mean * mean, 0.f);
            float sc = g3[tid] * rsqrtf(var + EPS);
            sc_s[tid] = sc;
            sh_s[tid] = b3[tid] - mean * sc;
        }
        __syncthreads();
        for (int i = 0; i < 16; ++i) {
            int idx = i * 65536 + (bid << 8) + tid;
            int hw = idx & 63;
            int ci = (idx >> 6) & 255;
            int b = idx >> 14;
            size_t base = ((size_t)(b * 64 + hw)) * 256 + ci;
            float f = conv3parts[base] + conv3parts[base + 1048576];
            f = f * sc_s[ci] + sh_s[ci];
            f = f >= 0.f ? f : NEG * f;
            a4[idx] = f2bf(f);
        }
    }
    gbar(bar, 7);

    // ---------------- phase 8: conv4 (16co x 16ks, atomic h4) ---------------
    {
        constexpr int CH = 4, NCHUNK = 8;
        typedef short (*BsT)[64][40];
        BsT Bs = (BsT)smem;
        int bco = bid & 15;
        int ks = bid >> 4;
        int wave = tid >> 6, lane = tid & 63, q = lane >> 4, l16 = lane & 15;
        const short* aBase = (const short*)a4 + (size_t)(wave * 16 + l16) * 16384 + ks * 1024 + q * 8;
        int r = tid >> 2, cc = tid & 3;
        const float* bg = w4 + (size_t)(bco * 64 + r) * 16384 + ks * 1024 + cc * 8;

        floatx4 acc[4];
#pragma unroll
        for (int nt = 0; nt < 4; ++nt) acc[nt] = (floatx4){0.f, 0.f, 0.f, 0.f};

        short8 nb[CH];
#pragma unroll
        for (int s = 0; s < CH; ++s) {
            float4 b0 = *(const float4*)(bg + s * 32);
            float4 b1 = *(const float4*)(bg + s * 32 + 4);
            nb[s][0] = (short)f2bf(b0.x); nb[s][1] = (short)f2bf(b0.y);
            nb[s][2] = (short)f2bf(b0.z); nb[s][3] = (short)f2bf(b0.w);
            nb[s][4] = (short)f2bf(b1.x); nb[s][5] = (short)f2bf(b1.y);
            nb[s][6] = (short)f2bf(b1.z); nb[s][7] = (short)f2bf(b1.w);
        }
#pragma unroll
        for (int s = 0; s < CH; ++s) *(short8*)&Bs[s][r][cc * 8] = nb[s];
        __syncthreads();

        for (int chunk = 0; chunk < NCHUNK; ++chunk) {
            bool has_next = (chunk + 1 < NCHUNK);
            if (has_next) {
#pragma unroll
                for (int s = 0; s < CH; ++s) {
                    int step = (chunk + 1) * CH + s;
                    float4 b0 = *(const float4*)(bg + step * 32);
                    float4 b1 = *(const float4*)(bg + step * 32 + 4);
                    nb[s][0] = (short)f2bf(b0.x); nb[s][1] = (short)f2bf(b0.y);
                    nb[s][2] = (short)f2bf(b0.z); nb[s][3] = (short)f2bf(b0.w);
                    nb[s][4] = (short)f2bf(b1.x); nb[s][5] = (short)f2bf(b1.y);
                    nb[s][6] = (short)f2bf(b1.z); nb[s][7] = (short)f2bf(b1.w);
                }
            }
#pragma unroll
            for (int s = 0; s < CH; ++s) {
                int step = chunk * CH + s;
                short8 af = *(const short8*)(aBase + step * 32);
#pragma unroll
                for (int nt = 0; nt < 4; ++nt) {
                    short8 bf = *(const short8*)&Bs[s][nt * 16 + l16][q * 8];
                    acc[nt] = __builtin_amdgcn_mfma_f32_16x16x32_bf16(af, bf, acc[nt], 0, 0, 0);
                }
            }
            if (has_next) {
                __syncthreads();
#pragma unroll
                for (int s = 0; s < CH; ++s) *(short8*)&Bs[s][r][cc * 8] = nb[s];
                __syncthreads();
            }
        }
#pragma unroll
        for (int nt = 0; nt < 4; ++nt)
#pragma unroll
            for (int rg = 0; rg < 4; ++rg) {
                int mg = wave * 16 + q * 4 + rg;
                int co = bco * 64 + nt * 16 + l16;
                atomicAdd(&h4[(size_t)mg * 1024 + co], acc[nt][rg]);
            }
    }
    gbar(bar, 8);

    // ---------------- phase 9: stats4 (16 blocks) ---------------------------
    if (bid < 16) {
        float* ls = (float*)smem;
        float* ls2 = ls + 256;
        int c = (bid << 6) + (tid & 63);
        int w = tid >> 6;
        float s = 0.f, s2 = 0.f;
        for (int r = w; r < 64; r += 4) {
            float v = h4[(size_t)r * 1024 + c];
            s += v; s2 += v * v;
        }
        ls[(w << 6) + (tid & 63)] = s;
        ls2[(w << 6) + (tid & 63)] = s2;
        __syncthreads();
        if (tid < 64) {
            float ts = ls[tid] + ls[64 + tid] + ls[128 + tid] + ls[192 + tid];
            float ts2 = ls2[tid] + ls2[64 + tid] + ls2[128 + tid] + ls2[192 + tid];
            atomicAdd(&st4[(bid << 6) + tid], ts);
            atomicAdd(&st4[1024 + (bid << 6) + tid], ts2);
        }
    }
    gbar(bar, 9);

    // ---------------- phase 10: conv5 (64 blocks) ---------------------------
    if (bid < 64) {
        int b = bid;
        float s = 0.f;
        for (int c = tid; c < 1024; c += 256) {
            float mean = st4[c] * (1.f / 64.f);
            float var = fmaxf(st4[1024 + c] * (1.f / 64.f) - mean * mean, 0.f);
            float sc = g4[c] * rsqrtf(var + EPS);
            float sh = b4[c] - mean * sc;
            float f = h4[(size_t)b * 1024 + c] * sc + sh;
            f = f >= 0.f ? f : NEG * f;
            s = fmaf(f, w5[c], s);
        }
#pragma unroll
        for (int off = 32; off > 0; off >>= 1) s += __shfl_down(s, off);
        float* ls = (float*)smem;
        if ((tid & 63) == 0) ls[tid >> 6] = s;
        __syncthreads();
        if (tid == 0) outF[b] = ls[0] + ls[1] + ls[2] + ls[3] + b5[0];
    }
}

// ----------------------------------------------------------------- launch ---
extern "C" void kernel_launch(void* const* d_in, const int* in_sizes, int n_in,
                              void* d_out, int out_size, void* d_ws, size_t ws_size,
                              hipStream_t stream) {
    (void)in_sizes; (void)n_in; (void)out_size; (void)ws_size;
    const float* input_data = (const float*)d_in[0];
    const float* w1 = (const float*)d_in[2];
    const float* g1 = (const float*)d_in[3];
    const float* b1 = (const float*)d_in[4];
    const float* w2 = (const float*)d_in[5];
    const float* g2 = (const float*)d_in[6];
    const float* b2 = (const float*)d_in[7];
    const float* w3 = (const float*)d_in[8];
    const float* g3 = (const float*)d_in[9];
    const float* b3 = (const float*)d_in[10];
    const float* w4 = (const float*)d_in[11];
    const float* g4 = (const float*)d_in[12];
    const float* b4 = (const float*)d_in[13];
    const float* w5 = (const float*)d_in[14];
    const float* b5 = (const float*)d_in[15];

    char* ws = (char*)d_ws;
    unsigned short* rendered   = (unsigned short*)(ws + 0);          //  9,469,952
    float*          conv1out   = (float*)(ws + 9469952);             // 16,777,216
    unsigned short* pad1       = (unsigned short*)(ws + 26247168);   // 10,616,832
    float*          conv2out   = (float*)(ws + 36864000);            //  8,388,608
    unsigned short* pad2       = (unsigned short*)(ws + 45252608);   //  6,553,600
    float*          conv3parts = (float*)(ws + 51806208);            //  8,388,608 (2 splits)
    unsigned short* a4         = (unsigned short*)(ws + 60194816);   //  2,097,152
    float*          h4         = (float*)(ws + 62291968);            //    262,144
    float*          st1        = (float*)(ws + 62554112);            //        512
    float*          st2        = (float*)(ws + 62554624);            //      1,024
    float*          st3        = (float*)(ws + 62555648);            //      2,048
    float*          st4        = (float*)(ws + 62557696);            //      8,192
    unsigned*       bar        = (unsigned*)(ws + 62565888);         //        256
    unsigned short* wT1        = (unsigned short*)(ws + 62566144);   //     61,440
    unsigned short* wT2        = (unsigned short*)(ws + 62627584);   //    409,600
    unsigned short* wT3        = (unsigned short*)(ws + 63037184);   //  1,638,400

    // zero h4 + st1..st4 + barrier counters (one contiguous memset)
    hipMemsetAsync(ws + 62291968, 0, 274176, stream);

    mega_kernel<<<256, 256, 0, stream>>>(
        input_data, w1, g1, b1, w2, g2, b2, w3, g3, b3, w4, g4, b4, w5, b5,
        rendered, conv1out, pad1, conv2out, pad2, conv3parts, a4, h4,
        st1, st2, st3, st4, wT1, wT2, wT3, bar, (float*)d_out);
}